// Round 13
// baseline (2141.949 us; speedup 1.0000x reference)
//
#include <hip/hip_runtime.h>

#define DT 0.042f
constexpr int B = 64, L = 1024, I = 128, H = 512;

// scan decomposition: 32 batch-groups x 8 column-slices = 256 blocks (1/CU).
constexpr int NG = 32;          // batch groups
constexpr int NS = 8;           // column slices == k-chunks (1 per wave)
constexpr int GB = B / NG;      // 2 batches per group
constexpr int SC = H / NS;      // 64 cols per slice / k per chunk

// ---------------------------------------------------------------------------
// Kernel 1: u = x @ x2h + bias -> staged into the all_states region of d_out
// ---------------------------------------------------------------------------
__global__ __launch_bounds__(256) void k_ugemm(const float* __restrict__ x,
                                               const float* __restrict__ w,
                                               const float* __restrict__ bias,
                                               float* __restrict__ u) {
    __shared__ __align__(16) float a_s[64][132];
    __shared__ __align__(16) float b_s[128][68];
    const int tx = threadIdx.x & 15;
    const int ty = threadIdx.x >> 4;
    const int row0 = blockIdx.x * 64;
    const int col0 = blockIdx.y * 64;

    for (int i = threadIdx.x; i < 64 * 32; i += 256) {
        int r = i >> 5, c4 = (i & 31) << 2;
        *(float4*)&a_s[r][c4] = *(const float4*)(x + (size_t)(row0 + r) * I + c4);
    }
    for (int i = threadIdx.x; i < 128 * 16; i += 256) {
        int k = i >> 4, c4 = (i & 15) << 2;
        *(float4*)&b_s[k][c4] = *(const float4*)(w + (size_t)k * H + col0 + c4);
    }
    __syncthreads();

    float acc[4][4] = {};
    for (int k = 0; k < I; k += 4) {
        float a4[4][4], b4[4][4];
        #pragma unroll
        for (int i = 0; i < 4; ++i) *(float4*)a4[i] = *(const float4*)&a_s[ty * 4 + i][k];
        #pragma unroll
        for (int kk = 0; kk < 4; ++kk) *(float4*)b4[kk] = *(const float4*)&b_s[k + kk][tx * 4];
        #pragma unroll
        for (int i = 0; i < 4; ++i)
            #pragma unroll
            for (int kk = 0; kk < 4; ++kk)
                #pragma unroll
                for (int j = 0; j < 4; ++j)
                    acc[i][j] += a4[i][kk] * b4[kk][j];
    }
    float4 bv = *(const float4*)&bias[col0 + tx * 4];
    #pragma unroll
    for (int i = 0; i < 4; ++i) {
        size_t r = (size_t)(row0 + ty * 4 + i);
        float4 o;
        o.x = acc[i][0] + bv.x; o.y = acc[i][1] + bv.y;
        o.z = acc[i][2] + bv.z; o.w = acc[i][3] + bv.w;
        *(float4*)&u[r * H + col0 + tx * 4] = o;
    }
}

// ---------------------------------------------------------------------------
// Kernel 2: the scan — round-5 champion EXACTLY, with two poll-critical-path
// fixes (R12 closed the model: step = vis+observe ~3300-3500 cy + ~900 cy
// compute; everything else is hidden):
//  (1) u-prefetch no longer gates the first poll check: it issues BETWEEN
//      the first poll pair and the backup pair (vmcnt ordering means a
//      pre-poll u-load forced the first check to drain its ~900cy latency).
//  (2) 2-deep software-pipelined poll: pairs A and B alternately in flight;
//      each check waits only its own pair (compiler emits vmcnt(2)-style
//      waits), halving the check cadence from ~RTT to ~RTT/2.
// Protocol, layouts, 3 barriers, publish order: byte-identical to round 5.
// ---------------------------------------------------------------------------
__global__ __launch_bounds__(512) void k_scan(float* __restrict__ su,
                                              const float* __restrict__ h2h,
                                              const float* __restrict__ gamma,
                                              const float* __restrict__ epsv,
                                              unsigned long long* __restrict__ wsq,
                                              float* __restrict__ hyfin) {
    __shared__ __align__(16) float hy_s[GB * H];        // [b][k]       4 KiB
    __shared__ __align__(16) float red[NS * GB * SC];   // [kc][b][cc]  4 KiB
    const int tid = threadIdx.x;
    const int g = blockIdx.x & 31;    // group (members stride-32 -> same XCD%8)
    const int s = blockIdx.x >> 5;    // column slice 0..7
    const int b0 = g * GB, c0 = s * SC;

    const int cc = tid & 63, kc = tid >> 6;       // compute map: 64 cols x 8 k-chunks
    const int scc = tid & 63, sb = (tid >> 6) & 1;  // state map (tid < 128)
    const int sc_ = c0 + scc;

    // h2h chunk: hreg[kk] = h2h[kc*64+kk][c0+cc] (R5 form: compiler streams
    // from L2 per step; R12 proved this is fully hidden under the sync wait)
    float hreg[64];
    {
        const float* hp = h2h + (size_t)(kc * 64) * H + c0 + cc;
        #pragma unroll
        for (int kk = 0; kk < 64; ++kk) hreg[kk] = hp[(size_t)kk * H];
    }

    float gam = 0.f, ep = 0.f;
    float* su_p = nullptr;
    if (tid < 128) {
        gam = gamma[sc_]; ep = epsv[sc_];
        su_p = su + (size_t)(b0 + sb) * L * H + sc_;
    }
    // poll: this thread's 2 qwords of the group's 1024-qword hy region
    unsigned long long* pollA = wsq + (size_t)b0 * H + (size_t)tid * 2;
    unsigned long long* pollB = pollA + (size_t)B * H;
    unsigned long long* dstA  = wsq + (size_t)(b0 + sb) * H + sc_;
    unsigned long long* dstB  = dstA + (size_t)B * H;

    float hy = 0.f, hz = 0.f;
    __syncthreads();

#define LDQ(p) __hip_atomic_load((p), __ATOMIC_RELAXED, __HIP_MEMORY_SCOPE_AGENT)

    for (int t = 0; t < L; ++t) {
        float uval = 0.f;
        if (t > 0) {
            unsigned long long* src = (t & 1) ? pollB : pollA;
            const unsigned tg = (unsigned)t;
            unsigned long long w0, w1;
            // pair A in flight first
            unsigned long long a0 = LDQ(src + 0), a1 = LDQ(src + 1);
            // u-prefetch issues AFTER pair A: hides under the spin, and the
            // A-check's waitcnt no longer drains it.
            if (tid < 128) uval = *su_p;
            // pair B in flight behind A
            unsigned long long b0q = LDQ(src + 0), b1q = LDQ(src + 1);
            for (;;) {
                if ((unsigned)(a0 >> 32) == tg && (unsigned)(a1 >> 32) == tg) {
                    w0 = a0; w1 = a1; break;
                }
                a0 = LDQ(src + 0); a1 = LDQ(src + 1);     // refill A behind B
                if ((unsigned)(b0q >> 32) == tg && (unsigned)(b1q >> 32) == tg) {
                    w0 = b0q; w1 = b1q; break;
                }
                b0q = LDQ(src + 0); b1q = LDQ(src + 1);   // refill B behind A
            }
            float2 hv;
            hv.x = __uint_as_float((unsigned)w0);
            hv.y = __uint_as_float((unsigned)w1);
            *(float2*)&hy_s[tid * 2] = hv;
        } else {
            if (tid < 128) uval = *su_p;
            *(float2*)&hy_s[tid * 2] = float2{0.f, 0.f};
        }
        __syncthreads();                          // (1) hy_s ready — phase lock

        // partial matmul: acc[b] = sum_{kk} hreg[kk] * hy[b][kc*64+kk]
        // hy_s reads are full-wave broadcasts (address uniform across lanes).
        float acc0 = 0.f, acc1 = 0.f;
        const int k0 = kc * 64;
        #pragma unroll
        for (int q = 0; q < 16; ++q) {
            const float4 y0 = *(const float4*)&hy_s[0 * H + k0 + q * 4];
            const float4 y1 = *(const float4*)&hy_s[1 * H + k0 + q * 4];
            acc0 += hreg[q * 4 + 0] * y0.x + hreg[q * 4 + 1] * y0.y
                  + hreg[q * 4 + 2] * y0.z + hreg[q * 4 + 3] * y0.w;
            acc1 += hreg[q * 4 + 0] * y1.x + hreg[q * 4 + 1] * y1.y
                  + hreg[q * 4 + 2] * y1.z + hreg[q * 4 + 3] * y1.w;
        }
        red[kc * (GB * SC) + 0 * SC + cc] = acc0;
        red[kc * (GB * SC) + 1 * SC + cc] = acc1;
        __syncthreads();                          // (2) partials ready

        if (tid < 128) {
            const float* rq = red + sb * SC + scc;
            float m0 = rq[0 * 128] + rq[1 * 128];
            float m1 = rq[2 * 128] + rq[3 * 128];
            float m2 = rq[4 * 128] + rq[5 * 128];
            float m3 = rq[6 * 128] + rq[7 * 128];
            const float xx = uval + ((m0 + m1) + (m2 + m3));
            const float cx = fminf(fmaxf(xx, -10.f), 10.f);  // tanh via exp, clamped
            const float e2 = __expf(2.f * cx);
            const float th = (e2 - 1.f) / (e2 + 1.f);
            hz += DT * (th - gam * hy - ep * hz);
            hy += DT * hz;
            // publish FIRST (critical path), bookkeeping after
            const unsigned long long wq =
                ((unsigned long long)(unsigned)(t + 1) << 32) | __float_as_uint(hy);
            __hip_atomic_store(((t + 1) & 1) ? dstB : dstA, wq,
                               __ATOMIC_RELAXED, __HIP_MEMORY_SCOPE_AGENT);
            *su_p = hy;                           // all_states[b][t][c]
            su_p += H;
            if (t == L - 1) hyfin[(size_t)(b0 + sb) * H + sc_] = hy;
        }
        __syncthreads();                          // (3) red/hy_s safe to overwrite
    }
#undef LDQ
}

extern "C" void kernel_launch(void* const* d_in, const int* in_sizes, int n_in,
                              void* d_out, int out_size, void* d_ws, size_t ws_size,
                              hipStream_t stream) {
    const float* x     = (const float*)d_in[0];
    const float* x2h   = (const float*)d_in[1];
    const float* h2h   = (const float*)d_in[2];
    const float* bias  = (const float*)d_in[3];
    const float* gamma = (const float*)d_in[4];
    const float* epsv  = (const float*)d_in[5];
    float* states = (float*)d_out;                      // (B, L, H)
    float* hyfin  = states + (size_t)B * L * H;         // (B, H)

    unsigned long long* wsq = (unsigned long long*)d_ws;  // 2 x (B*H) tagged qwords

    hipMemsetAsync(d_ws, 0, 2ull * B * H * 8, stream);  // tag 0 != any awaited t>=1
    dim3 g1(B * L / 64, H / 64);
    k_ugemm<<<g1, 256, 0, stream>>>(x, x2h, bias, states);
    k_scan<<<NG * NS, 512, 0, stream>>>(states, h2h, gamma, epsv, wsq, hyfin);
}

// Round 14
// 1885.494 us; speedup vs baseline: 1.1360x; 1.1360x over previous
//
#include <hip/hip_runtime.h>

#define DT 0.042f
constexpr int B = 64, L = 1024, I = 128, H = 512;

// scan decomposition: 32 batch-groups x 8 column-slices = 256 blocks (1/CU).
constexpr int NG = 32;          // batch groups
constexpr int NS = 8;           // column slices == k-chunks (1 per wave)
constexpr int GB = B / NG;      // 2 batches per group
constexpr int SC = H / NS;      // 64 cols per slice / k per chunk

// ---------------------------------------------------------------------------
// Kernel 1: u = x @ x2h + bias -> staged into the all_states region of d_out
// ---------------------------------------------------------------------------
__global__ __launch_bounds__(256) void k_ugemm(const float* __restrict__ x,
                                               const float* __restrict__ w,
                                               const float* __restrict__ bias,
                                               float* __restrict__ u) {
    __shared__ __align__(16) float a_s[64][132];
    __shared__ __align__(16) float b_s[128][68];
    const int tx = threadIdx.x & 15;
    const int ty = threadIdx.x >> 4;
    const int row0 = blockIdx.x * 64;
    const int col0 = blockIdx.y * 64;

    for (int i = threadIdx.x; i < 64 * 32; i += 256) {
        int r = i >> 5, c4 = (i & 31) << 2;
        *(float4*)&a_s[r][c4] = *(const float4*)(x + (size_t)(row0 + r) * I + c4);
    }
    for (int i = threadIdx.x; i < 128 * 16; i += 256) {
        int k = i >> 4, c4 = (i & 15) << 2;
        *(float4*)&b_s[k][c4] = *(const float4*)(w + (size_t)k * H + col0 + c4);
    }
    __syncthreads();

    float acc[4][4] = {};
    for (int k = 0; k < I; k += 4) {
        float a4[4][4], b4[4][4];
        #pragma unroll
        for (int i = 0; i < 4; ++i) *(float4*)a4[i] = *(const float4*)&a_s[ty * 4 + i][k];
        #pragma unroll
        for (int kk = 0; kk < 4; ++kk) *(float4*)b4[kk] = *(const float4*)&b_s[k + kk][tx * 4];
        #pragma unroll
        for (int i = 0; i < 4; ++i)
            #pragma unroll
            for (int kk = 0; kk < 4; ++kk)
                #pragma unroll
                for (int j = 0; j < 4; ++j)
                    acc[i][j] += a4[i][kk] * b4[kk][j];
    }
    float4 bv = *(const float4*)&bias[col0 + tx * 4];
    #pragma unroll
    for (int i = 0; i < 4; ++i) {
        size_t r = (size_t)(row0 + ty * 4 + i);
        float4 o;
        o.x = acc[i][0] + bv.x; o.y = acc[i][1] + bv.y;
        o.z = acc[i][2] + bv.z; o.w = acc[i][3] + bv.w;
        *(float4*)&u[r * H + col0 + tx * 4] = o;
    }
}

// ---------------------------------------------------------------------------
// Kernel 2: the scan — round-5 champion with the poll WIDENED, not deepened.
// R11/R13 showed poll-aggression backfires (L3 contention: FETCH rises, time
// rises). Here each thread's 2 contiguous 16B-aligned qwords are fetched by
// ONE global_load_dwordx4 sc1 (same L3-coherent flag the agent atomic uses):
// same bytes, same visibility point, HALF the L3 requests chip-wide. No
// tearing: both qwords sit in one 128B line, producer stores are 8B atomics.
// Secondary (ordering-proof cleanup): red[] parity-double-buffered -> bar(3)
// deleted (reads@t < bar1@t+1 < bar1@t+2 < next same-parity write).
// Everything else byte-identical to round 5 (1870 us champion).
// ---------------------------------------------------------------------------
__global__ __launch_bounds__(512, 2) void k_scan(float* __restrict__ su,
                                              const float* __restrict__ h2h,
                                              const float* __restrict__ gamma,
                                              const float* __restrict__ epsv,
                                              unsigned long long* __restrict__ wsq,
                                              float* __restrict__ hyfin) {
    __shared__ __align__(16) float hy_s[GB * H];        // [b][k]       4 KiB
    __shared__ __align__(16) float red[2][NS * GB * SC];// parity bufs  8 KiB
    const int tid = threadIdx.x;
    const int g = blockIdx.x & 31;    // group (members stride-32 -> same XCD%8)
    const int s = blockIdx.x >> 5;    // column slice 0..7
    const int b0 = g * GB, c0 = s * SC;

    const int cc = tid & 63, kc = tid >> 6;       // compute map: 64 cols x 8 k-chunks
    const int scc = tid & 63, sb = (tid >> 6) & 1;  // state map (tid < 128)
    const int sc_ = c0 + scc;

    // h2h chunk: hreg[kk] = h2h[kc*64+kk][c0+cc] (R5 form; R12 proved the
    // per-step L2 re-stream is fully hidden under the sync wait)
    float hreg[64];
    {
        const float* hp = h2h + (size_t)(kc * 64) * H + c0 + cc;
        #pragma unroll
        for (int kk = 0; kk < 64; ++kk) hreg[kk] = hp[(size_t)kk * H];
    }

    float gam = 0.f, ep = 0.f;
    float* su_p = nullptr;
    if (tid < 128) {
        gam = gamma[sc_]; ep = epsv[sc_];
        su_p = su + (size_t)(b0 + sb) * L * H + sc_;
    }
    // poll: this thread's 2 contiguous qwords (16B-aligned) of the group region
    unsigned long long* pollA = wsq + (size_t)b0 * H + (size_t)tid * 2;
    unsigned long long* pollB = pollA + (size_t)B * H;
    unsigned long long* dstA  = wsq + (size_t)(b0 + sb) * H + sc_;
    unsigned long long* dstB  = dstA + (size_t)B * H;

    float hy = 0.f, hz = 0.f;
    __syncthreads();

    for (int t = 0; t < L; ++t) {
        float uval = 0.f;
        if (tid < 128) uval = *su_p;              // u[t] prefetch (R5 placement)

        if (t > 0) {
            unsigned long long* src = (t & 1) ? pollB : pollA;
            const unsigned tg = (unsigned)t;
            ulonglong2 pw;
            // ONE 16B L3-coherent load replaces two 8B atomic loads.
            asm volatile("global_load_dwordx4 %0, %1, off sc1\n\t"
                         "s_waitcnt vmcnt(0)"
                         : "=v"(pw) : "v"(src) : "memory");
            while ((unsigned)(pw.x >> 32) != tg || (unsigned)(pw.y >> 32) != tg) {
                asm volatile("global_load_dwordx4 %0, %1, off sc1\n\t"
                             "s_waitcnt vmcnt(0)"
                             : "=v"(pw) : "v"(src) : "memory");
            }
            float2 hv;
            hv.x = __uint_as_float((unsigned)pw.x);
            hv.y = __uint_as_float((unsigned)pw.y);
            *(float2*)&hy_s[tid * 2] = hv;
        } else {
            *(float2*)&hy_s[tid * 2] = float2{0.f, 0.f};
        }
        __syncthreads();                          // (1) hy_s ready — phase lock

        // partial matmul: acc[b] = sum_{kk} hreg[kk] * hy[b][kc*64+kk]
        // hy_s reads are full-wave broadcasts (address uniform across lanes).
        float acc0 = 0.f, acc1 = 0.f;
        const int k0 = kc * 64;
        #pragma unroll
        for (int q = 0; q < 16; ++q) {
            const float4 y0 = *(const float4*)&hy_s[0 * H + k0 + q * 4];
            const float4 y1 = *(const float4*)&hy_s[1 * H + k0 + q * 4];
            acc0 += hreg[q * 4 + 0] * y0.x + hreg[q * 4 + 1] * y0.y
                  + hreg[q * 4 + 2] * y0.z + hreg[q * 4 + 3] * y0.w;
            acc1 += hreg[q * 4 + 0] * y1.x + hreg[q * 4 + 1] * y1.y
                  + hreg[q * 4 + 2] * y1.z + hreg[q * 4 + 3] * y1.w;
        }
        float* rp = red[t & 1];
        rp[kc * (GB * SC) + 0 * SC + cc] = acc0;
        rp[kc * (GB * SC) + 1 * SC + cc] = acc1;
        __syncthreads();                          // (2) partials ready

        if (tid < 128) {
            const float* rq = red[t & 1] + sb * SC + scc;
            float m0 = rq[0 * 128] + rq[1 * 128];
            float m1 = rq[2 * 128] + rq[3 * 128];
            float m2 = rq[4 * 128] + rq[5 * 128];
            float m3 = rq[6 * 128] + rq[7 * 128];
            const float xx = uval + ((m0 + m1) + (m2 + m3));
            const float cx = fminf(fmaxf(xx, -10.f), 10.f);  // tanh via exp, clamped
            const float e2 = __expf(2.f * cx);
            const float th = (e2 - 1.f) / (e2 + 1.f);
            hz += DT * (th - gam * hy - ep * hz);
            hy += DT * hz;
            // publish FIRST (critical path), bookkeeping after
            const unsigned long long wq =
                ((unsigned long long)(unsigned)(t + 1) << 32) | __float_as_uint(hy);
            __hip_atomic_store(((t + 1) & 1) ? dstB : dstA, wq,
                               __ATOMIC_RELAXED, __HIP_MEMORY_SCOPE_AGENT);
            *su_p = hy;                           // all_states[b][t][c]
            su_p += H;
            if (t == L - 1) hyfin[(size_t)(b0 + sb) * H + sc_] = hy;
        }
        // no barrier(3): red parity + ordering proof make it redundant.
    }
}

extern "C" void kernel_launch(void* const* d_in, const int* in_sizes, int n_in,
                              void* d_out, int out_size, void* d_ws, size_t ws_size,
                              hipStream_t stream) {
    const float* x     = (const float*)d_in[0];
    const float* x2h   = (const float*)d_in[1];
    const float* h2h   = (const float*)d_in[2];
    const float* bias  = (const float*)d_in[3];
    const float* gamma = (const float*)d_in[4];
    const float* epsv  = (const float*)d_in[5];
    float* states = (float*)d_out;                      // (B, L, H)
    float* hyfin  = states + (size_t)B * L * H;         // (B, H)

    unsigned long long* wsq = (unsigned long long*)d_ws;  // 2 x (B*H) tagged qwords

    hipMemsetAsync(d_ws, 0, 2ull * B * H * 8, stream);  // tag 0 != any awaited t>=1
    dim3 g1(B * L / 64, H / 64);
    k_ugemm<<<g1, 256, 0, stream>>>(x, x2h, bias, states);
    k_scan<<<NG * NS, 512, 0, stream>>>(states, h2h, gamma, epsv, wsq, hyfin);
}

// Round 15
// 1862.106 us; speedup vs baseline: 1.1503x; 1.0126x over previous
//
#include <hip/hip_runtime.h>

#define DT 0.042f
constexpr int B = 64, L = 1024, I = 128, H = 512;

// scan decomposition: 64 groups (1 batch each) x 8 column-slices = 512 blocks,
// 2 per CU. Co-CU pair = DIFFERENT groups (independent recurrences): while one
// block's waves stall on the exchange poll (s_waitcnt, ~no issue), the other
// block's waves compute — hardware-scheduler TLP hides the sync RTT.
// Decode: g = (blk&31) | ((blk>>8)<<5), s = (blk&255)>>5 -> pair (blk,blk+256)
// differs in g by 32; group members stride-32 (same XCD%8, champion heuristic).
constexpr int NS = 8;           // column slices == k-chunks (1 per wave)
constexpr int SC = H / NS;      // 64 cols per slice / k per chunk

// ---------------------------------------------------------------------------
// Kernel 1: u = x @ x2h + bias -> staged into the all_states region of d_out
// ---------------------------------------------------------------------------
__global__ __launch_bounds__(256) void k_ugemm(const float* __restrict__ x,
                                               const float* __restrict__ w,
                                               const float* __restrict__ bias,
                                               float* __restrict__ u) {
    __shared__ __align__(16) float a_s[64][132];
    __shared__ __align__(16) float b_s[128][68];
    const int tx = threadIdx.x & 15;
    const int ty = threadIdx.x >> 4;
    const int row0 = blockIdx.x * 64;
    const int col0 = blockIdx.y * 64;

    for (int i = threadIdx.x; i < 64 * 32; i += 256) {
        int r = i >> 5, c4 = (i & 31) << 2;
        *(float4*)&a_s[r][c4] = *(const float4*)(x + (size_t)(row0 + r) * I + c4);
    }
    for (int i = threadIdx.x; i < 128 * 16; i += 256) {
        int k = i >> 4, c4 = (i & 15) << 2;
        *(float4*)&b_s[k][c4] = *(const float4*)(w + (size_t)k * H + col0 + c4);
    }
    __syncthreads();

    float acc[4][4] = {};
    for (int k = 0; k < I; k += 4) {
        float a4[4][4], b4[4][4];
        #pragma unroll
        for (int i = 0; i < 4; ++i) *(float4*)a4[i] = *(const float4*)&a_s[ty * 4 + i][k];
        #pragma unroll
        for (int kk = 0; kk < 4; ++kk) *(float4*)b4[kk] = *(const float4*)&b_s[k + kk][tx * 4];
        #pragma unroll
        for (int i = 0; i < 4; ++i)
            #pragma unroll
            for (int kk = 0; kk < 4; ++kk)
                #pragma unroll
                for (int j = 0; j < 4; ++j)
                    acc[i][j] += a4[i][kk] * b4[kk][j];
    }
    float4 bv = *(const float4*)&bias[col0 + tx * 4];
    #pragma unroll
    for (int i = 0; i < 4; ++i) {
        size_t r = (size_t)(row0 + ty * 4 + i);
        float4 o;
        o.x = acc[i][0] + bv.x; o.y = acc[i][1] + bv.y;
        o.z = acc[i][2] + bv.z; o.w = acc[i][3] + bv.w;
        *(float4*)&u[r * H + col0 + tx * 4] = o;
    }
}

// ---------------------------------------------------------------------------
// Kernel 2: the scan — R5 protocol, 1-batch groups, 2 independent blocks/CU.
// Per step: thread tid polls ONE tagged qword hy[g][tid] (producer = slice
// tid>>6; wave w consumes exactly slice w -> wave-aligned), writes hy_s[tid];
// bar(1); wave kc: 16 broadcast b128 reads x 64 FMA; red[t&1] write; bar(2);
// 64 reducer threads sum 8 partials, update state, publish tag t+1.
// red parity + hy_s write-after-bar2 ordering proofs make bar(3) redundant.
// Cross-block reuse safety: publish of t+1 follows bar(2) which follows all
// waves' polls of t => every producer consumed t-1; slot (t+1)&1 dead.
// All-resident: 512 blocks, capacity >= 4/CU (6KB LDS, ~52 VGPR) -> no
// deadlock at any packing. Transport: agent-scope relaxed atomics via L3.
// ---------------------------------------------------------------------------
__global__ __launch_bounds__(512, 2) void k_scan(float* __restrict__ su,
                                              const float* __restrict__ h2h,
                                              const float* __restrict__ gamma,
                                              const float* __restrict__ epsv,
                                              unsigned long long* __restrict__ wsq,
                                              float* __restrict__ hyfin) {
    __shared__ __align__(16) float hy_s[H];             // [k]          2 KiB
    __shared__ __align__(16) float red[2][H];           // parity bufs  4 KiB
    const int tid = threadIdx.x;
    const int blk = blockIdx.x;
    const int g = (blk & 31) | ((blk >> 8) << 5);       // batch 0..63
    const int s = (blk & 255) >> 5;                     // slice 0..7
    const int c0 = s * SC;

    const int cc = tid & 63, kc = tid >> 6;             // compute map
    const int k0 = kc * 64;

    // h2h chunk: hreg[kk] = h2h[kc*64+kk][c0+cc] (compiler streams from L2
    // per step; R12 proved this is fully hidden under the sync wait)
    float hreg[64];
    {
        const float* hp = h2h + (size_t)k0 * H + c0 + cc;
        #pragma unroll
        for (int kk = 0; kk < 64; ++kk) hreg[kk] = hp[(size_t)kk * H];
    }

    float gam = 0.f, ep = 0.f;
    float* su_p = nullptr;
    if (tid < SC) {                                     // reducer/state threads
        gam = gamma[c0 + tid]; ep = epsv[c0 + tid];
        su_p = su + (size_t)g * L * H + c0 + tid;
    }
    // poll: thread tid owns hy[g][tid] (one qword); publish: col c0+tid
    unsigned long long* pollA = wsq + (size_t)g * H + tid;
    unsigned long long* pollB = pollA + (size_t)B * H;
    unsigned long long* dstA  = wsq + (size_t)g * H + c0 + tid;
    unsigned long long* dstB  = dstA + (size_t)B * H;

    float hy = 0.f, hz = 0.f;
    __syncthreads();

    for (int t = 0; t < L; ++t) {
        float uval = 0.f;
        if (tid < SC) uval = *su_p;                     // u[t] prefetch

        if (t > 0) {
            unsigned long long* src = (t & 1) ? pollB : pollA;
            const unsigned tg = (unsigned)t;
            unsigned long long w0 = __hip_atomic_load(src, __ATOMIC_RELAXED,
                                                      __HIP_MEMORY_SCOPE_AGENT);
            while ((unsigned)(w0 >> 32) != tg)
                w0 = __hip_atomic_load(src, __ATOMIC_RELAXED,
                                       __HIP_MEMORY_SCOPE_AGENT);
            hy_s[tid] = __uint_as_float((unsigned)w0);
        } else {
            hy_s[tid] = 0.f;
        }
        __syncthreads();                                // (1) hy_s ready

        // partial matmul: acc = sum_{kk} hreg[kk] * hy[k0+kk]
        // hy_s reads are full-wave broadcasts (address uniform across lanes).
        float acc = 0.f;
        #pragma unroll
        for (int q = 0; q < 16; ++q) {
            const float4 y = *(const float4*)&hy_s[k0 + q * 4];
            acc += hreg[q * 4 + 0] * y.x + hreg[q * 4 + 1] * y.y
                 + hreg[q * 4 + 2] * y.z + hreg[q * 4 + 3] * y.w;
        }
        red[t & 1][kc * SC + cc] = acc;
        __syncthreads();                                // (2) partials ready

        if (tid < SC) {
            const float* rq = red[t & 1] + tid;
            float m0 = rq[0 * SC] + rq[1 * SC];
            float m1 = rq[2 * SC] + rq[3 * SC];
            float m2 = rq[4 * SC] + rq[5 * SC];
            float m3 = rq[6 * SC] + rq[7 * SC];
            const float xx = uval + ((m0 + m1) + (m2 + m3));
            const float cx = fminf(fmaxf(xx, -10.f), 10.f);  // tanh via exp
            const float e2 = __expf(2.f * cx);
            const float th = (e2 - 1.f) / (e2 + 1.f);
            hz += DT * (th - gam * hy - ep * hz);
            hy += DT * hz;
            // publish FIRST (critical path), bookkeeping after
            const unsigned long long wq =
                ((unsigned long long)(unsigned)(t + 1) << 32) | __float_as_uint(hy);
            __hip_atomic_store(((t + 1) & 1) ? dstB : dstA, wq,
                               __ATOMIC_RELAXED, __HIP_MEMORY_SCOPE_AGENT);
            *su_p = hy;                                 // all_states[g][t][c]
            su_p += H;
            if (t == L - 1) hyfin[(size_t)g * H + c0 + tid] = hy;
        }
        // no barrier(3): red parity + hy_s-write-after-bar2 ordering proofs.
    }
}

extern "C" void kernel_launch(void* const* d_in, const int* in_sizes, int n_in,
                              void* d_out, int out_size, void* d_ws, size_t ws_size,
                              hipStream_t stream) {
    const float* x     = (const float*)d_in[0];
    const float* x2h   = (const float*)d_in[1];
    const float* h2h   = (const float*)d_in[2];
    const float* bias  = (const float*)d_in[3];
    const float* gamma = (const float*)d_in[4];
    const float* epsv  = (const float*)d_in[5];
    float* states = (float*)d_out;                      // (B, L, H)
    float* hyfin  = states + (size_t)B * L * H;         // (B, H)

    unsigned long long* wsq = (unsigned long long*)d_ws;  // 2 x (B*H) tagged qwords

    hipMemsetAsync(d_ws, 0, 2ull * B * H * 8, stream);  // tag 0 != any awaited t>=1
    dim3 g1(B * L / 64, H / 64);
    k_ugemm<<<g1, 256, 0, stream>>>(x, x2h, bias, states);
    k_scan<<<512, 512, 0, stream>>>(states, h2h, gamma, epsv, wsq, hyfin);
}